// Round 1
// baseline (1334.471 us; speedup 1.0000x reference)
//
#include <hip/hip_runtime.h>
#include <math.h>

#define LVID 2048
#define LTXT 512
#define DMOD 512
#define LTOT 2560
#define LOG2_GAMMA (-0.15200309344504995f)   // log2(0.9)

// ---------------------------------------------------------------- loss
__global__ __launch_bounds__(256) void k_loss(const float* __restrict__ lw,
                                              float* __restrict__ loss_out) {
  __shared__ float red[256];
  int tid = threadIdx.x;
  float s = 0.f;
  for (int idx = blockIdx.x * 256 + tid; idx < LVID * LVID; idx += gridDim.x * 256) {
    int i = idx >> 11, j = idx & (LVID - 1);
    if (i != j) s += 1.f / (1.f + expf(-lw[idx]));
  }
  red[tid] = s; __syncthreads();
  for (int st = 128; st > 0; st >>= 1) { if (tid < st) red[tid] += red[tid + st]; __syncthreads(); }
  if (tid == 0) atomicAdd(loss_out, red[0] * (1.f / (float)(LVID * LVID)));
}

// ------------------------------------------- LN1 + xpos(q,k) + sine pos (fused)
__global__ __launch_bounds__(256) void k_ln1(
    const float* __restrict__ src_vid, const float* __restrict__ src_txt,
    const float* __restrict__ w, const float* __restrict__ b,
    float* __restrict__ src2, float* __restrict__ qb, float* __restrict__ kb,
    float* __restrict__ posb) {
  int row = blockIdx.x;       // 0..2559
  int t = threadIdx.x;        // handles cols 2t, 2t+1
  const float* xs = (row < LVID) ? (src_vid + (size_t)row * DMOD)
                                 : (src_txt + (size_t)(row - LVID) * DMOD);
  float x0 = xs[2 * t], x1 = xs[2 * t + 1];
  __shared__ float red[256];
  red[t] = x0 + x1; __syncthreads();
  for (int st = 128; st > 0; st >>= 1) { if (t < st) red[t] += red[t + st]; __syncthreads(); }
  float mu = red[0] * (1.f / DMOD);
  __syncthreads();
  float d0 = x0 - mu, d1 = x1 - mu;
  red[t] = d0 * d0 + d1 * d1; __syncthreads();
  for (int st = 128; st > 0; st >>= 1) { if (t < st) red[t] += red[t + st]; __syncthreads(); }
  float inv = rsqrtf(red[0] * (1.f / DMOD) + 1e-5f);
  float y0 = d0 * inv * w[2 * t] + b[2 * t];
  float y1 = d1 * inv * w[2 * t + 1] + b[2 * t + 1];
  size_t base = (size_t)row * DMOD;
  src2[base + 2 * t] = y0; src2[base + 2 * t + 1] = y1;
  if (row < LVID) {
    // xpos applied to the RAW src_vid row (reference adds xpos(src_vid) to src2)
    float l = (float)row;
    float sj = (2.f * t + 204.8f) * (1.f / 716.8f);          // (2j + 0.4d)/(1.4d)
    float scale = powf(sj, l * (1.f / 512.f));
    float invfreq = powf(10000.f, -(float)t * (1.f / 256.f));
    float ang = l * invfreq;
    float sn, cs; sincosf(ang, &sn, &cs);
    float cq = cs * scale, sq = sn * scale;
    float pq0 = x0 * cq - x1 * sq, pq1 = x1 * cq + x0 * sq;
    float isc = 1.f / scale;
    float ck = cs * isc, sk = sn * isc;
    float pk0 = x0 * ck - x1 * sk, pk1 = x1 * ck + x0 * sk;
    posb[base + 2 * t] = pq0; posb[base + 2 * t + 1] = pq1;
    qb[base + 2 * t] = y0 + pq0; qb[base + 2 * t + 1] = y1 + pq1;
    kb[base + 2 * t] = y0 + pk0; kb[base + 2 * t + 1] = y1 + pk1;
  } else {
    int l = row - LVID;
    float xe = (float)(l + 1) * (6.28318530717958647692f / 512.000001f);
    float dimt = powf(10000.f, (float)t * (1.f / 256.f));
    float a = xe / dimt;
    posb[base + 2 * t] = sinf(a);
    posb[base + 2 * t + 1] = cosf(a);
  }
}

// ---------------------------------------------------------------- generic LN
__global__ __launch_bounds__(256) void k_ln(
    const float* __restrict__ x, const float* __restrict__ x2,
    const float* __restrict__ w, const float* __restrict__ b,
    float* __restrict__ o) {
  int row = blockIdx.x, t = threadIdx.x;
  size_t base = (size_t)row * DMOD;
  float x0 = x[base + 2 * t], x1 = x[base + 2 * t + 1];
  if (x2) { x0 += x2[base + 2 * t]; x1 += x2[base + 2 * t + 1]; }
  __shared__ float red[256];
  red[t] = x0 + x1; __syncthreads();
  for (int st = 128; st > 0; st >>= 1) { if (t < st) red[t] += red[t + st]; __syncthreads(); }
  float mu = red[0] * (1.f / DMOD);
  __syncthreads();
  float d0 = x0 - mu, d1 = x1 - mu;
  red[t] = d0 * d0 + d1 * d1; __syncthreads();
  for (int st = 128; st > 0; st >>= 1) { if (t < st) red[t] += red[t + st]; __syncthreads(); }
  float inv = rsqrtf(red[0] * (1.f / DMOD) + 1e-5f);
  o[base + 2 * t] = d0 * inv * w[2 * t] + b[2 * t];
  o[base + 2 * t + 1] = d1 * inv * w[2 * t + 1] + b[2 * t + 1];
}

// ------------------------------------------------------- residual add #1
__global__ __launch_bounds__(256) void k_add1(
    const float* __restrict__ src_vid, const float* __restrict__ src_txt,
    const float* __restrict__ atto, const float* __restrict__ src2,
    const float* __restrict__ posb, float* __restrict__ srcA) {
  int idx = blockIdx.x * 256 + threadIdx.x;    // 0 .. 2560*512-1
  int row = idx >> 9;
  float base = (row < LVID) ? src_vid[idx] : src_txt[idx - LVID * DMOD];
  float mid  = (row < LVID) ? atto[idx] : src2[idx];
  srcA[idx] = base + mid + posb[idx];
}

// ------------------------------------------------- tiled fp32 GEMM: C=(A@W^T+b)*alpha
// A: MxK row-major, W: NxK row-major. ACT=1 -> exact GELU epilogue.
template <int ACT>
__global__ __launch_bounds__(256) void k_gemm(
    const float* __restrict__ A, const float* __restrict__ W,
    const float* __restrict__ bias, float* __restrict__ C,
    int M, int N, int K, float alpha) {
  __shared__ float sA[16][65];
  __shared__ float sB[16][65];
  int tid = threadIdx.x;
  int bn = blockIdx.x * 64, bm = blockIdx.y * 64;
  int tx = tid & 15, ty = tid >> 4;
  float acc[4][4] = {};
  for (int k0 = 0; k0 < K; k0 += 16) {
    for (int i = tid; i < 1024; i += 256) {
      int m = i >> 4, kk = i & 15;
      sA[kk][m] = A[(size_t)(bm + m) * K + k0 + kk];
    }
    for (int i = tid; i < 1024; i += 256) {
      int n = i >> 4, kk = i & 15;
      sB[kk][n] = W[(size_t)(bn + n) * K + k0 + kk];
    }
    __syncthreads();
#pragma unroll
    for (int kk = 0; kk < 16; kk++) {
      float av[4], bv[4];
#pragma unroll
      for (int i = 0; i < 4; i++) av[i] = sA[kk][ty * 4 + i];
#pragma unroll
      for (int j = 0; j < 4; j++) bv[j] = sB[kk][tx * 4 + j];
#pragma unroll
      for (int i = 0; i < 4; i++)
#pragma unroll
        for (int j = 0; j < 4; j++) acc[i][j] += av[i] * bv[j];
    }
    __syncthreads();
  }
#pragma unroll
  for (int i = 0; i < 4; i++) {
    int m = bm + ty * 4 + i;
#pragma unroll
    for (int j = 0; j < 4; j++) {
      int n = bn + tx * 4 + j;
      float v = (acc[i][j] + bias[n]) * alpha;
      if (ACT == 1) v = 0.5f * v * (1.f + erff(v * 0.70710678118654752f));
      C[(size_t)m * N + n] = v;
    }
  }
}

// --------------------------- retention attention, online softmax, 32x32 tiles
// logits = (qh . kh) * mask ; masked entries contribute exp(0)=1 to softmax.
// Tiles entirely masked (future, or decay-underflow delta>900) -> uniform weight.
__global__ __launch_bounds__(256) void k_attn(
    const float* __restrict__ qh, const float* __restrict__ kh,
    const float* __restrict__ vh, const float* __restrict__ lw,
    float* __restrict__ outp) {
  int i0 = blockIdx.x * 32;
  int h  = blockIdx.y;
  int tid = threadIdx.x;
  __shared__ float sQ[32][65], sK[32][65], sV[32][65];
  __shared__ float sE[32][33], sWm[32][33];
  __shared__ float sTM[32][8];
  __shared__ float sM[32], sAl[32], sZ[32];
  for (int idx = tid; idx < 2048; idx += 256) {
    int r = idx >> 6, d = idx & 63;
    sQ[r][d] = qh[(size_t)(i0 + r) * DMOD + h * 64 + d];
  }
  if (tid < 32) { sM[tid] = 0.f; sZ[tid] = 0.f; }
  float O[8];
#pragma unroll
  for (int i = 0; i < 8; i++) O[i] = 0.f;
  int r_s = tid & 31, cg = tid >> 5;     // score mapping: row, col-group(4)
  int r_o = tid >> 3, d0 = (tid & 7) * 8; // output mapping: row, 8 dims
  for (int j0 = 0; j0 < LVID; j0 += 32) {
    bool fm = (j0 > i0 + 31) || ((i0 - (j0 + 31)) > 900);  // fully-masked tile
    __syncthreads();  // S0: prior-tile consumers done
    for (int idx = tid; idx < 2048; idx += 256) {
      int r = idx >> 6, d = idx & 63;
      sV[r][d] = vh[(size_t)(j0 + r) * DMOD + h * 64 + d];
    }
    if (!fm) {
      for (int idx = tid; idx < 2048; idx += 256) {
        int r = idx >> 6, d = idx & 63;
        sK[r][d] = kh[(size_t)(j0 + r) * DMOD + h * 64 + d];
      }
      for (int idx = tid; idx < 1024; idx += 256) {
        int r = idx >> 5, c = idx & 31;
        sWm[r][c] = lw[(size_t)(i0 + r) * LVID + j0 + c];
      }
    }
    __syncthreads();  // S1: tiles loaded
    if (!fm) {
      float acc[4] = {0.f, 0.f, 0.f, 0.f};
      for (int kk = 0; kk < 64; kk++) {
        float qv = sQ[r_s][kk];
#pragma unroll
        for (int cc = 0; cc < 4; cc++) acc[cc] += qv * sK[cg * 4 + cc][kk];
      }
      float tmax = -1e30f;
#pragma unroll
      for (int cc = 0; cc < 4; cc++) {
        int qi = i0 + r_s, kj = j0 + cg * 4 + cc;
        float m;
        if (kj > qi) m = 0.f;
        else if (kj == qi) m = 1.f;
        else {
          float decay = exp2f((float)(qi - kj) * LOG2_GAMMA);
          m = decay / (1.f + expf(-sWm[r_s][cg * 4 + cc]));
        }
        float lg = acc[cc] * m;
        sE[r_s][cg * 4 + cc] = lg;      // store raw logit
        tmax = fmaxf(tmax, lg);
      }
      sTM[r_s][cg] = tmax;
    }
    __syncthreads();  // S2: logits + tile-max ready
    if (tid < 32 && !fm) {
      float tm = sTM[tid][0];
#pragma unroll
      for (int g = 1; g < 8; g++) tm = fmaxf(tm, sTM[tid][g]);
      float mn = fmaxf(sM[tid], tm);
      float al = expf(sM[tid] - mn);
      sM[tid] = mn; sAl[tid] = al;
      sZ[tid] *= al;
    }
    __syncthreads();  // S3: running max / alpha ready
    if (!fm) {
      float mr = sM[r_s];
#pragma unroll
      for (int cc = 0; cc < 4; cc++)
        sE[r_s][cg * 4 + cc] = expf(sE[r_s][cg * 4 + cc] - mr);
    }
    __syncthreads();  // S4: e ready
    if (tid < 32) {
      if (fm) sZ[tid] += 32.f * expf(-sM[tid]);
      else {
        float z = 0.f;
#pragma unroll
        for (int c = 0; c < 32; c++) z += sE[tid][c];
        sZ[tid] += z;
      }
    }
    if (fm) {
      float ev = expf(-sM[r_o]);   // uniform weight exp(0 - m)
      for (int c = 0; c < 32; c++) {
#pragma unroll
        for (int dd = 0; dd < 8; dd++) O[dd] += ev * sV[c][d0 + dd];
      }
    } else {
      float al = sAl[r_o];
#pragma unroll
      for (int dd = 0; dd < 8; dd++) O[dd] *= al;
      for (int c = 0; c < 32; c++) {
        float ev = sE[r_o][c];
#pragma unroll
        for (int dd = 0; dd < 8; dd++) O[dd] += ev * sV[c][d0 + dd];
      }
    }
  }
  __syncthreads();
  float zi = 1.f / sZ[r_o];
#pragma unroll
  for (int dd = 0; dd < 8; dd++)
    outp[(size_t)(i0 + r_o) * DMOD + h * 64 + d0 + dd] = O[dd] * zi;
}

// ----------------------------------------------------------------- launcher
extern "C" void kernel_launch(void* const* d_in, const int* in_sizes, int n_in,
                              void* d_out, int out_size, void* d_ws, size_t ws_size,
                              hipStream_t stream) {
  const float* src_vid = (const float*)d_in[0];
  const float* src_txt = (const float*)d_in[1];
  const float* ln1_w = (const float*)d_in[2];
  const float* ln1_b = (const float*)d_in[3];
  const float* wq = (const float*)d_in[4];
  const float* bq = (const float*)d_in[5];
  const float* wk = (const float*)d_in[6];
  const float* bk = (const float*)d_in[7];
  const float* wv = (const float*)d_in[8];
  const float* bv = (const float*)d_in[9];
  const float* wo = (const float*)d_in[10];
  const float* bo = (const float*)d_in[11];
  const float* lin1_w = (const float*)d_in[12];
  const float* lin1_b = (const float*)d_in[13];
  const float* lin2_w = (const float*)d_in[14];
  const float* lin2_b = (const float*)d_in[15];
  const float* ln2_w = (const float*)d_in[16];
  const float* ln2_b = (const float*)d_in[17];
  const float* ln3_w = (const float*)d_in[18];
  const float* ln3_b = (const float*)d_in[19];
  const float* lw = (const float*)d_in[20];

  float* ws = (float*)d_ws;
  float* out = (float*)d_out;
  // workspace layout (floats). aliases are lifetime-checked:
  float* src2 = ws;                 // [0, 1310720)          live: ln1 .. add1
  float* posb = ws + 1310720;       // [1310720, 2621440)    live: ln1 .. add1
  float* qb   = ws + 2621440;       // [2621440, 3670016)    live: ln1 .. qh-gemm
  float* kb   = ws + 3670016;       // [3670016, 4718592)    live: ln1 .. kh-gemm
  float* qhb  = ws + 4718592;       // [4718592, 5767168)    live: gemm .. attn
  float* khb  = ws + 5767168;       // [5767168, 6815744)    live: gemm .. attn
  float* vhb  = ws + 6815744;       // [6815744, 7864320)    live: gemm .. attn
  float* srcA = ws + 7864320;       // [7864320, 9175040)    live: add1 .. ln3
  float* s2b  = ws + 9175040;       // [9175040, 10485760)   live: ln2 .. ffn1
  float* vatt = qb;                 // alias (qb dead after qh-gemm)
  float* atto = kb;                 // alias (kb dead after kh-gemm)
  float* hid  = ws + 4718592;       // alias qhb..vhb (dead after attn), 2621440 floats
  float* ffo  = ws + 2621440;       // alias qb+part of kb (dead after add1), 1310720 floats

  // zero the loss accumulator slot (d_out is poisoned 0xAA before each launch)
  hipMemsetAsync((char*)d_out + (size_t)1310720 * sizeof(float), 0, sizeof(float), stream);
  k_loss<<<512, 256, 0, stream>>>(lw, out + 1310720);

  k_ln1<<<LTOT, 256, 0, stream>>>(src_vid, src_txt, ln1_w, ln1_b, src2, qb, kb, posb);

  k_gemm<0><<<dim3(8, 32), 256, 0, stream>>>(qb,   wq, bq, qhb, LVID, DMOD, DMOD, 0.125f);
  k_gemm<0><<<dim3(8, 32), 256, 0, stream>>>(kb,   wk, bk, khb, LVID, DMOD, DMOD, 1.f);
  k_gemm<0><<<dim3(8, 32), 256, 0, stream>>>(src2, wv, bv, vhb, LVID, DMOD, DMOD, 1.f);

  k_attn<<<dim3(64, 8), 256, 0, stream>>>(qhb, khb, vhb, lw, vatt);

  k_gemm<0><<<dim3(8, 32), 256, 0, stream>>>(vatt, wo, bo, atto, LVID, DMOD, DMOD, 1.f);

  k_add1<<<5120, 256, 0, stream>>>(src_vid, src_txt, atto, src2, posb, srcA);
  k_ln<<<LTOT, 256, 0, stream>>>(srcA, nullptr, ln2_w, ln2_b, s2b);

  k_gemm<1><<<dim3(16, 40), 256, 0, stream>>>(s2b, lin1_w, lin1_b, hid, LTOT, 1024, DMOD, 1.f);
  k_gemm<0><<<dim3(8, 40), 256, 0, stream>>>(hid, lin2_w, lin2_b, ffo, LTOT, DMOD, 1024, 1.f);

  // final residual + LN3, written straight to d_out (vid rows then txt rows are
  // contiguous in the flat output, so out[row*512+c] covers both chunks)
  k_ln<<<LTOT, 256, 0, stream>>>(srcA, ffo, ln3_w, ln3_b, out);
}

// Round 2
// 282.980 us; speedup vs baseline: 4.7158x; 4.7158x over previous
//
#include <hip/hip_runtime.h>
#include <hip/hip_bf16.h>
#include <math.h>

#define LVID 2048
#define LTXT 512
#define DMOD 512
#define LTOT 2560
#define LOG2_GAMMA (-0.15200309344504995f)   // log2(0.9)

typedef __bf16 bf16x8 __attribute__((ext_vector_type(8)));
typedef float f32x4 __attribute__((ext_vector_type(4)));

__device__ inline f32x4 mfma_bf16(bf16x8 a, bf16x8 b, f32x4 c) {
  return __builtin_amdgcn_mfma_f32_16x16x32_bf16(a, b, c, 0, 0, 0);
}

// async global->LDS, 16B per lane; LDS dest = wave-uniform base + lane*16
__device__ inline void gload_lds16(const void* g, void* l) {
  __builtin_amdgcn_global_load_lds(
      (const __attribute__((address_space(1))) void*)g,
      (__attribute__((address_space(3))) void*)l, 16, 0, 0);
}

// ---------------------------------------------------- fp32 weights -> bf16
// concatenated dst: wq|wk|wv|wo|lin1|lin2 (element counts 4x262144 + 2x524288)
__global__ __launch_bounds__(256) void k_cvt_w(
    const float* __restrict__ wq, const float* __restrict__ wk,
    const float* __restrict__ wv, const float* __restrict__ wo,
    const float* __restrict__ l1, const float* __restrict__ l2,
    __hip_bfloat16* __restrict__ dst) {
  int i4 = blockIdx.x * 256 + threadIdx.x;   // float4 index, 0..524287
  const float* s; int base;
  if (i4 < 131072)      { if (i4 < 65536)  { s = wq; base = 0; }      else { s = wk; base = 65536; } }
  else if (i4 < 262144) { if (i4 < 196608) { s = wv; base = 131072; } else { s = wo; base = 196608; } }
  else if (i4 < 393216) { s = l1; base = 262144; }
  else                  { s = l2; base = 393216; }
  float4 v = ((const float4*)s)[i4 - base];
  __hip_bfloat16 o[4] = {__float2bfloat16(v.x), __float2bfloat16(v.y),
                         __float2bfloat16(v.z), __float2bfloat16(v.w)};
  *(uint2*)(dst + (size_t)i4 * 4) = *(uint2*)o;
}

// ------------------------------------ loss + premask (gamma^D * sigmoid) fused
__global__ __launch_bounds__(256) void k_loss_mask(
    const float* __restrict__ lw, float* __restrict__ premask,
    float* __restrict__ loss_out) {
  __shared__ float red[256];
  int tid = threadIdx.x;
  int idx0 = (blockIdx.x * 256 + tid) * 8;
  float s = 0.f;
#pragma unroll
  for (int e = 0; e < 8; e++) {
    int idx = idx0 + e;
    int i = idx >> 11, j = idx & 2047;
    float sig = 1.f / (1.f + expf(-lw[idx]));
    if (i != j) s += sig;
    float pm = (j > i) ? 0.f
             : ((j == i) ? 1.f : exp2f((float)(i - j) * LOG2_GAMMA) * sig);
    premask[idx] = pm;
  }
  red[tid] = s; __syncthreads();
  for (int st = 128; st > 0; st >>= 1) { if (tid < st) red[tid] += red[tid + st]; __syncthreads(); }
  if (tid == 0) atomicAdd(loss_out, red[0] * (1.f / 4194304.f));
}

// ---------------- LN1 + xpos(q,k) + sine pos, fp32 + bf16 outputs (fused)
__global__ __launch_bounds__(256) void k_ln1(
    const float* __restrict__ src_vid, const float* __restrict__ src_txt,
    const float* __restrict__ w, const float* __restrict__ b,
    float* __restrict__ src2, __hip_bfloat16* __restrict__ src2b,
    __hip_bfloat16* __restrict__ qb, __hip_bfloat16* __restrict__ kb,
    float* __restrict__ posb) {
  int row = blockIdx.x;       // 0..2559
  int t = threadIdx.x;        // cols 2t, 2t+1
  const float* xs = (row < LVID) ? (src_vid + (size_t)row * DMOD)
                                 : (src_txt + (size_t)(row - LVID) * DMOD);
  float x0 = xs[2 * t], x1 = xs[2 * t + 1];
  __shared__ float red[256];
  red[t] = x0 + x1; __syncthreads();
  for (int st = 128; st > 0; st >>= 1) { if (t < st) red[t] += red[t + st]; __syncthreads(); }
  float mu = red[0] * (1.f / DMOD);
  __syncthreads();
  float d0 = x0 - mu, d1 = x1 - mu;
  red[t] = d0 * d0 + d1 * d1; __syncthreads();
  for (int st = 128; st > 0; st >>= 1) { if (t < st) red[t] += red[t + st]; __syncthreads(); }
  float inv = rsqrtf(red[0] * (1.f / DMOD) + 1e-5f);
  float y0 = d0 * inv * w[2 * t] + b[2 * t];
  float y1 = d1 * inv * w[2 * t + 1] + b[2 * t + 1];
  size_t base = (size_t)row * DMOD;
  src2[base + 2 * t] = y0; src2[base + 2 * t + 1] = y1;
  if (row < LVID) {
    src2b[base + 2 * t] = __float2bfloat16(y0);
    src2b[base + 2 * t + 1] = __float2bfloat16(y1);
    float l = (float)row;
    float sj = (2.f * t + 204.8f) * (1.f / 716.8f);
    float scale = powf(sj, l * (1.f / 512.f));
    float invfreq = powf(10000.f, -(float)t * (1.f / 256.f));
    float ang = l * invfreq;
    float sn, cs; sincosf(ang, &sn, &cs);
    float cq = cs * scale, sq = sn * scale;
    float pq0 = x0 * cq - x1 * sq, pq1 = x1 * cq + x0 * sq;
    float isc = 1.f / scale;
    float ck = cs * isc, sk = sn * isc;
    float pk0 = x0 * ck - x1 * sk, pk1 = x1 * ck + x0 * sk;
    posb[base + 2 * t] = pq0; posb[base + 2 * t + 1] = pq1;
    qb[base + 2 * t] = __float2bfloat16(y0 + pq0);
    qb[base + 2 * t + 1] = __float2bfloat16(y1 + pq1);
    kb[base + 2 * t] = __float2bfloat16(y0 + pk0);
    kb[base + 2 * t + 1] = __float2bfloat16(y1 + pk1);
  } else {
    int l = row - LVID;
    float xe = (float)(l + 1) * (6.28318530717958647692f / 512.000001f);
    float dimt = powf(10000.f, (float)t * (1.f / 256.f));
    float a = xe / dimt;
    posb[base + 2 * t] = sinf(a);
    posb[base + 2 * t + 1] = cosf(a);
  }
}

// ---------------------------------------------------------------- generic LN
__global__ __launch_bounds__(256) void k_ln(
    const float* __restrict__ x, const float* __restrict__ x2,
    const float* __restrict__ w, const float* __restrict__ b,
    float* __restrict__ o, __hip_bfloat16* __restrict__ obf) {
  int row = blockIdx.x, t = threadIdx.x;
  size_t base = (size_t)row * DMOD;
  float x0 = x[base + 2 * t], x1 = x[base + 2 * t + 1];
  if (x2) { x0 += x2[base + 2 * t]; x1 += x2[base + 2 * t + 1]; }
  __shared__ float red[256];
  red[t] = x0 + x1; __syncthreads();
  for (int st = 128; st > 0; st >>= 1) { if (t < st) red[t] += red[t + st]; __syncthreads(); }
  float mu = red[0] * (1.f / DMOD);
  __syncthreads();
  float d0 = x0 - mu, d1 = x1 - mu;
  red[t] = d0 * d0 + d1 * d1; __syncthreads();
  for (int st = 128; st > 0; st >>= 1) { if (t < st) red[t] += red[t + st]; __syncthreads(); }
  float inv = rsqrtf(red[0] * (1.f / DMOD) + 1e-5f);
  float v0 = d0 * inv * w[2 * t] + b[2 * t];
  float v1 = d1 * inv * w[2 * t + 1] + b[2 * t + 1];
  if (o)   { o[base + 2 * t] = v0; o[base + 2 * t + 1] = v1; }
  if (obf) { obf[base + 2 * t] = __float2bfloat16(v0);
             obf[base + 2 * t + 1] = __float2bfloat16(v1); }
}

// ------------------------------------------- residual add for txt rows only
__global__ __launch_bounds__(256) void k_add1txt(
    const float* __restrict__ src_txt, const float* __restrict__ src2,
    const float* __restrict__ posb, float* __restrict__ srcA) {
  int idx = blockIdx.x * 256 + threadIdx.x;   // 0..262143
  int g = LVID * DMOD + idx;
  srcA[g] = src_txt[idx] + src2[g] + posb[g];
}

// ----------------------------- bf16 MFMA GEMM: C = (A @ W^T + bias) * alpha
// A: MxK bf16 row-major, W: NxK bf16 row-major. 64x64 tile, BK=32, 4 waves.
// ACT=1: exact GELU. OMODE: 0=f32 out, 1=bf16 out, 2=f32 out + res1 + res2.
template <int ACT, int OMODE>
__global__ __launch_bounds__(256) void k_mfma_gemm(
    const __hip_bfloat16* __restrict__ A, const __hip_bfloat16* __restrict__ W,
    const float* __restrict__ bias, void* __restrict__ Cv,
    const float* __restrict__ res1, const float* __restrict__ res2,
    int M, int N, int K, float alpha) {
  __shared__ __hip_bfloat16 sA[64 * 32];
  __shared__ __hip_bfloat16 sB[64 * 32];
  int tid = threadIdx.x;
  int lane = tid & 63, w = tid >> 6;
  int bm = blockIdx.y * 64, bn = blockIdx.x * 64;
  int wm = w & 1, wn = w >> 1;
  int srow = lane >> 2, scol = (lane & 3) * 8;
  const __hip_bfloat16* gA = A + (size_t)(bm + 16 * w + srow) * K + scol;
  const __hip_bfloat16* gB = W + (size_t)(bn + 16 * w + srow) * K + scol;
  __hip_bfloat16* lA = sA + w * 512;
  __hip_bfloat16* lB = sB + w * 512;
  f32x4 acc[2][2];
  {
    f32x4 z = {0.f, 0.f, 0.f, 0.f};
    acc[0][0] = z; acc[0][1] = z; acc[1][0] = z; acc[1][1] = z;
  }
  int ar0 = (wm * 32 + (lane & 15)) * 32 + (lane >> 4) * 8;
  int br0 = (wn * 32 + (lane & 15)) * 32 + (lane >> 4) * 8;
  for (int k0 = 0; k0 < K; k0 += 32) {
    __syncthreads();                // prior LDS reads done
    gload_lds16(gA, lA);
    gload_lds16(gB, lB);
    gA += 32; gB += 32;
    __syncthreads();                // staging drained (vmcnt(0) at barrier)
    bf16x8 a0 = *(const bf16x8*)&sA[ar0];
    bf16x8 a1 = *(const bf16x8*)&sA[ar0 + 512];
    bf16x8 b0 = *(const bf16x8*)&sB[br0];
    bf16x8 b1 = *(const bf16x8*)&sB[br0 + 512];
    acc[0][0] = mfma_bf16(a0, b0, acc[0][0]);
    acc[0][1] = mfma_bf16(a0, b1, acc[0][1]);
    acc[1][0] = mfma_bf16(a1, b0, acc[1][0]);
    acc[1][1] = mfma_bf16(a1, b1, acc[1][1]);
  }
#pragma unroll
  for (int t = 0; t < 2; t++) {
#pragma unroll
    for (int u = 0; u < 2; u++) {
      int n = bn + wn * 32 + 16 * u + (lane & 15);
      float bs = bias[n];
#pragma unroll
      for (int r = 0; r < 4; r++) {
        int m = bm + wm * 32 + 16 * t + (lane >> 4) * 4 + r;
        float v = (acc[t][u][r] + bs) * alpha;
        if (ACT == 1) v = 0.5f * v * (1.f + erff(v * 0.70710678118654752f));
        size_t off = (size_t)m * N + n;
        if (OMODE == 0)      ((float*)Cv)[off] = v;
        else if (OMODE == 1) ((__hip_bfloat16*)Cv)[off] = __float2bfloat16(v);
        else                 ((float*)Cv)[off] = v + res1[off] + res2[off];
      }
    }
  }
}

// ------------------------------- per-head column sums of V (for uniform tiles)
__global__ __launch_bounds__(64) void k_vtot(const __hip_bfloat16* __restrict__ vh,
                                             float* __restrict__ Vtot) {
  int h = blockIdx.x, c = blockIdx.y, d = threadIdx.x;
  float s = 0.f;
  for (int j = 0; j < 64; j++)
    s += __bfloat162float(vh[(size_t)(c * 64 + j) * DMOD + h * 64 + d]);
  atomicAdd(&Vtot[h * 64 + d], s);
}

// --------------------- retention attention: MFMA flash with uniform-tile skip
// logits = (qh.kh)*premask; masked entries contribute exp(0-m). Tiles fully
// masked (future or decay-underflow) handled in O(1) via Vtot - Vact.
__global__ __launch_bounds__(256) void k_attn(
    const __hip_bfloat16* __restrict__ qh, const __hip_bfloat16* __restrict__ kh,
    const __hip_bfloat16* __restrict__ vh, const float* __restrict__ premask,
    const float* __restrict__ Vtot, __hip_bfloat16* __restrict__ outp) {
  __shared__ __hip_bfloat16 sQ[64][72];
  __shared__ __hip_bfloat16 sK[64][72];
  __shared__ __hip_bfloat16 sVt[64][72];   // transposed: [d][j]
  __shared__ __hip_bfloat16 sP[64][72];
  __shared__ float sVa[4][64];
  int i0 = blockIdx.x * 64, h = blockIdx.y;
  int tid = threadIdx.x, lane = tid & 63, w = tid >> 6;
  {  // stage Q tile (bf16 global, row-major into padded LDS)
    int r = tid >> 2, c0 = (tid & 3) * 16;
    const __hip_bfloat16* g = qh + (size_t)(i0 + r) * DMOD + h * 64 + c0;
    *(uint4*)&sQ[r][c0] = *(const uint4*)g;
    *(uint4*)&sQ[r][c0 + 8] = *(const uint4*)(g + 8);
  }
  int thi = i0 >> 6;                               // diagonal tile
  int tlo = (i0 > 900) ? ((i0 - 900) >> 6) : 0;    // first non-underflow tile
  int q4 = lane >> 4, c16 = lane & 15;
  float rm[4] = {0.f, 0.f, 0.f, 0.f};   // running max (>=0: zero logits exist)
  float rz[4] = {0.f, 0.f, 0.f, 0.f};
  f32x4 O[4];
  { f32x4 z = {0.f, 0.f, 0.f, 0.f}; O[0] = z; O[1] = z; O[2] = z; O[3] = z; }
  float vacc = 0.f;
  int kr = tid >> 2, kc = (tid & 3) * 16;          // K staging map
  int vd = tid & 63, vq = tid >> 6;                // V staging map (transpose)
  uint4 pk0, pk1;
  union { __hip_bfloat16 b[8]; uint4 u; } pv0, pv1;
  {  // prefetch tile tlo
    const __hip_bfloat16* gk = kh + (size_t)(tlo * 64 + kr) * DMOD + h * 64 + kc;
    pk0 = *(const uint4*)gk; pk1 = *(const uint4*)(gk + 8);
    const __hip_bfloat16* gv = vh + (size_t)(tlo * 64 + vq * 16) * DMOD + h * 64 + vd;
#pragma unroll
    for (int j = 0; j < 8; j++) pv0.b[j] = gv[(size_t)j * DMOD];
#pragma unroll
    for (int j = 0; j < 8; j++) pv1.b[j] = gv[(size_t)(j + 8) * DMOD];
  }
  for (int t = tlo; t <= thi; t++) {
    __syncthreads();               // prior tile's LDS reads complete
    *(uint4*)&sK[kr][kc] = pk0;
    *(uint4*)&sK[kr][kc + 8] = pk1;
    *(uint4*)&sVt[vd][vq * 16] = pv0.u;
    *(uint4*)&sVt[vd][vq * 16 + 8] = pv1.u;
#pragma unroll
    for (int j = 0; j < 8; j++) vacc += __bfloat162float(pv0.b[j]);
#pragma unroll
    for (int j = 0; j < 8; j++) vacc += __bfloat162float(pv1.b[j]);
    __syncthreads();               // staging visible
    if (t < thi) {                 // prefetch next tile (overlaps compute)
      const __hip_bfloat16* gk = kh + (size_t)((t + 1) * 64 + kr) * DMOD + h * 64 + kc;
      pk0 = *(const uint4*)gk; pk1 = *(const uint4*)(gk + 8);
      const __hip_bfloat16* gv = vh + (size_t)((t + 1) * 64 + vq * 16) * DMOD + h * 64 + vd;
#pragma unroll
      for (int j = 0; j < 8; j++) pv0.b[j] = gv[(size_t)j * DMOD];
#pragma unroll
      for (int j = 0; j < 8; j++) pv1.b[j] = gv[(size_t)(j + 8) * DMOD];
    }
    // ---- S = Q K^T (wave w owns q-rows w*16..w*16+15)
    bf16x8 aq0 = *(const bf16x8*)&sQ[w * 16 + c16][q4 * 8];
    bf16x8 aq1 = *(const bf16x8*)&sQ[w * 16 + c16][32 + q4 * 8];
    f32x4 S[4];
#pragma unroll
    for (int nt = 0; nt < 4; nt++) {
      f32x4 z = {0.f, 0.f, 0.f, 0.f};
      bf16x8 bk0 = *(const bf16x8*)&sK[nt * 16 + c16][q4 * 8];
      bf16x8 bk1 = *(const bf16x8*)&sK[nt * 16 + c16][32 + q4 * 8];
      z = mfma_bf16(aq0, bk0, z);
      z = mfma_bf16(aq1, bk1, z);
      S[nt] = z;
    }
    // ---- mask -> logits (C-layout: row = q4*4+r, col = nt*16+c16)
    float lg[4][4];
    float tmax[4] = {-3.0e38f, -3.0e38f, -3.0e38f, -3.0e38f};
    int mrow = i0 + w * 16 + q4 * 4;
    int mcolb = t * 64 + c16;
#pragma unroll
    for (int nt = 0; nt < 4; nt++) {
#pragma unroll
      for (int r = 0; r < 4; r++) {
        float mk = premask[(size_t)(mrow + r) * 2048 + mcolb + nt * 16];
        float v = S[nt][r] * mk;
        lg[nt][r] = v;
        tmax[r] = fmaxf(tmax[r], v);
      }
    }
#pragma unroll
    for (int s = 1; s < 16; s <<= 1) {
#pragma unroll
      for (int r = 0; r < 4; r++)
        tmax[r] = fmaxf(tmax[r], __shfl_xor(tmax[r], s, 64));
    }
    float al[4];
#pragma unroll
    for (int r = 0; r < 4; r++) {
      float mn = fmaxf(rm[r], tmax[r]);
      al[r] = expf(rm[r] - mn);
      rm[r] = mn;
    }
    float zp[4] = {0.f, 0.f, 0.f, 0.f};
#pragma unroll
    for (int nt = 0; nt < 4; nt++) {
#pragma unroll
      for (int r = 0; r < 4; r++) {
        float e = expf(lg[nt][r] - rm[r]);
        zp[r] += e;
        sP[w * 16 + q4 * 4 + r][nt * 16 + c16] = __float2bfloat16(e);
      }
    }
#pragma unroll
    for (int s = 1; s < 16; s <<= 1) {
#pragma unroll
      for (int r = 0; r < 4; r++)
        zp[r] += __shfl_xor(zp[r], s, 64);
    }
#pragma unroll
    for (int r = 0; r < 4; r++) rz[r] = rz[r] * al[r] + zp[r];
#pragma unroll
    for (int dt = 0; dt < 4; dt++)
#pragma unroll
      for (int r = 0; r < 4; r++) O[dt][r] *= al[r];
    // ---- O += P V  (P re-read in A-layout from own wave's rows; DS in-order)
    bf16x8 ap0 = *(const bf16x8*)&sP[w * 16 + c16][q4 * 8];
    bf16x8 ap1 = *(const bf16x8*)&sP[w * 16 + c16][32 + q4 * 8];
#pragma unroll
    for (int dt = 0; dt < 4; dt++) {
      bf16x8 bv0 = *(const bf16x8*)&sVt[dt * 16 + c16][q4 * 8];
      bf16x8 bv1 = *(const bf16x8*)&sVt[dt * 16 + c16][32 + q4 * 8];
      O[dt] = mfma_bf16(ap0, bv0, O[dt]);
      O[dt] = mfma_bf16(ap1, bv1, O[dt]);
    }
  }
  sVa[vq][vd] = vacc;
  __syncthreads();
  float nu = (float)(2048 - 64 * (thi - tlo + 1));  // # uniform (zero-logit) cols
#pragma unroll
  for (int dt = 0; dt < 4; dt++) {
    int d = dt * 16 + c16;
    float va = sVa[0][d] + sVa[1][d] + sVa[2][d] + sVa[3][d];
    float vu = Vtot[h * 64 + d] - va;
#pragma unroll
    for (int r = 0; r < 4; r++) {
      float eu = expf(-rm[r]);
      float o = (O[dt][r] + eu * vu) / (rz[r] + nu * eu);
      outp[(size_t)(i0 + w * 16 + q4 * 4 + r) * DMOD + h * 64 + d] = __float2bfloat16(o);
    }
  }
}

// ----------------------------------------------------------------- launcher
extern "C" void kernel_launch(void* const* d_in, const int* in_sizes, int n_in,
                              void* d_out, int out_size, void* d_ws, size_t ws_size,
                              hipStream_t stream) {
  const float* src_vid = (const float*)d_in[0];
  const float* src_txt = (const float*)d_in[1];
  const float* ln1_w = (const float*)d_in[2];
  const float* ln1_b = (const float*)d_in[3];
  const float* wq = (const float*)d_in[4];
  const float* bq = (const float*)d_in[5];
  const float* wk = (const float*)d_in[6];
  const float* bk = (const float*)d_in[7];
  const float* wv = (const float*)d_in[8];
  const float* bv = (const float*)d_in[9];
  const float* wo = (const float*)d_in[10];
  const float* bo = (const float*)d_in[11];
  const float* lin1_w = (const float*)d_in[12];
  const float* lin1_b = (const float*)d_in[13];
  const float* lin2_w = (const float*)d_in[14];
  const float* lin2_b = (const float*)d_in[15];
  const float* ln2_w = (const float*)d_in[16];
  const float* ln2_b = (const float*)d_in[17];
  const float* ln3_w = (const float*)d_in[18];
  const float* ln3_b = (const float*)d_in[19];
  const float* lw = (const float*)d_in[20];
  float* out = (float*)d_out;

  // workspace layout (byte offsets), peak 38.5 MiB < 40 MiB proven:
  //  [0,16M)      premask (dies after attn) -> srcA[0,5M), s2b[5M,7.5M), hid[7.5M,12.5M)
  //  [16M,20M)    bf16 weights (whole launch)
  //  [20M,25M)    src2 f32 (dies after add1txt) -> ffo f32
  //  [25M,30M)    posb f32
  //  [30M,32M)    qb bf16 -> khb bf16
  //  [32M,34M)    kb bf16 -> vhb bf16
  //  [34M,36.5M)  src2 bf16 -> vatt bf16 (2M)
  //  [36.5M,38.5M) qhb bf16 ; [38.5M,+2K) Vtot f32
  char* wsb = (char*)d_ws;
  float* premask = (float*)(wsb + 0);
  float* srcA    = (float*)(wsb + 0);
  __hip_bfloat16* s2b  = (__hip_bfloat16*)(wsb + 5242880);
  __hip_bfloat16* hidb = (__hip_bfloat16*)(wsb + 7864320);
  __hip_bfloat16* wqb  = (__hip_bfloat16*)(wsb + 16777216);
  __hip_bfloat16* wkb  = wqb + 262144;
  __hip_bfloat16* wvb  = wqb + 524288;
  __hip_bfloat16* wob  = wqb + 786432;
  __hip_bfloat16* l1b  = wqb + 1048576;
  __hip_bfloat16* l2b  = wqb + 1572864;
  float* src2f = (float*)(wsb + 20971520);
  float* ffo   = (float*)(wsb + 20971520);
  float* posb  = (float*)(wsb + 26214400);
  __hip_bfloat16* qbb   = (__hip_bfloat16*)(wsb + 31457280);
  __hip_bfloat16* khb   = (__hip_bfloat16*)(wsb + 31457280);
  __hip_bfloat16* kbb   = (__hip_bfloat16*)(wsb + 33554432);
  __hip_bfloat16* vhb   = (__hip_bfloat16*)(wsb + 33554432);
  __hip_bfloat16* s2vb  = (__hip_bfloat16*)(wsb + 35651584);
  __hip_bfloat16* vattb = (__hip_bfloat16*)(wsb + 35651584);
  __hip_bfloat16* qhb   = (__hip_bfloat16*)(wsb + 38273024);
  float* Vtot = (float*)(wsb + 40370176);

  hipMemsetAsync(out + 1310720, 0, sizeof(float), stream);   // loss slot
  hipMemsetAsync(Vtot, 0, 512 * sizeof(float), stream);

  k_cvt_w<<<2048, 256, 0, stream>>>(wq, wk, wv, wo, lin1_w, lin2_w, wqb);
  k_loss_mask<<<2048, 256, 0, stream>>>(lw, premask, out + 1310720);
  k_ln1<<<LTOT, 256, 0, stream>>>(src_vid, src_txt, ln1_w, ln1_b,
                                  src2f, s2vb, qbb, kbb, posb);

  k_mfma_gemm<0,1><<<dim3(8, 32), 256, 0, stream>>>(qbb, wqb, bq, qhb,
      nullptr, nullptr, 2048, 512, 512, 0.125f);
  k_mfma_gemm<0,1><<<dim3(8, 32), 256, 0, stream>>>(kbb, wkb, bk, khb,
      nullptr, nullptr, 2048, 512, 512, 1.f);
  k_mfma_gemm<0,1><<<dim3(8, 32), 256, 0, stream>>>(s2vb, wvb, bv, vhb,
      nullptr, nullptr, 2048, 512, 512, 1.f);

  k_vtot<<<dim3(8, 32), 64, 0, stream>>>(vhb, Vtot);
  k_attn<<<dim3(32, 8), 256, 0, stream>>>(qhb, khb, vhb, premask, Vtot, vattb);

  // O-proj with fused residual: srcA(vid) = vatt@wo^T + bo + src_vid + posb
  k_mfma_gemm<0,2><<<dim3(8, 32), 256, 0, stream>>>(vattb, wob, bo, srcA,
      src_vid, posb, 2048, 512, 512, 1.f);
  k_add1txt<<<1024, 256, 0, stream>>>(src_txt, src2f, posb, srcA);

  k_ln<<<LTOT, 256, 0, stream>>>(srcA, nullptr, ln2_w, ln2_b, nullptr, s2b);
  k_mfma_gemm<1,1><<<dim3(16, 40), 256, 0, stream>>>(s2b, l1b, lin1_b, hidb,
      nullptr, nullptr, 2560, 1024, 512, 1.f);
  k_mfma_gemm<0,0><<<dim3(8, 40), 256, 0, stream>>>(hidb, l2b, lin2_b, ffo,
      nullptr, nullptr, 2560, 512, 1024, 1.f);

  k_ln<<<LTOT, 256, 0, stream>>>(srcA, ffo, ln3_w, ln3_b, out, nullptr);
}

// Round 3
// 238.252 us; speedup vs baseline: 5.6011x; 1.1877x over previous
//
#include <hip/hip_runtime.h>
#include <hip/hip_bf16.h>
#include <math.h>

#define LVID 2048
#define LTXT 512
#define DMOD 512
#define LTOT 2560
#define LOG2_GAMMA (-0.15200309344504995f)   // log2(0.9)
#define LOG2E 1.4426950408889634f

typedef __bf16 bf16x8 __attribute__((ext_vector_type(8)));
typedef float f32x4 __attribute__((ext_vector_type(4)));

__device__ inline f32x4 mfma_bf16(bf16x8 a, bf16x8 b, f32x4 c) {
  return __builtin_amdgcn_mfma_f32_16x16x32_bf16(a, b, c, 0, 0, 0);
}

__device__ inline void gload_lds16(const void* g, void* l) {
  __builtin_amdgcn_global_load_lds(
      (const __attribute__((address_space(1))) void*)g,
      (__attribute__((address_space(3))) void*)l, 16, 0, 0);
}

union U8 { __hip_bfloat16 b[8]; uint4 u; };

// ---------------- prep: loss + premask2(= gamma^D * sigmoid * log2e) + weight cvt
__global__ __launch_bounds__(256) void k_prep(
    const float* __restrict__ lw, float* __restrict__ premask2,
    float* __restrict__ loss_out,
    const float* __restrict__ wq, const float* __restrict__ wk,
    const float* __restrict__ wv, const float* __restrict__ wo,
    const float* __restrict__ l1, const float* __restrict__ l2,
    __hip_bfloat16* __restrict__ dst) {
  int tid = threadIdx.x;
  if (blockIdx.x < 2048) {            // mask + loss part
    __shared__ float red[256];
    int idx0 = (blockIdx.x * 256 + tid) * 8;
    float s = 0.f;
#pragma unroll
    for (int e = 0; e < 8; e++) {
      int idx = idx0 + e;
      int i = idx >> 11, j = idx & 2047;
      float sig = 1.f / (1.f + expf(-lw[idx]));
      if (i != j) s += sig;
      float pm = (j > i) ? 0.f
               : ((j == i) ? 1.f : exp2f((float)(i - j) * LOG2_GAMMA) * sig);
      premask2[idx] = pm * LOG2E;
    }
    red[tid] = s; __syncthreads();
    for (int st = 128; st > 0; st >>= 1) { if (tid < st) red[tid] += red[tid + st]; __syncthreads(); }
    if (tid == 0) atomicAdd(loss_out, red[0] * (1.f / 4194304.f));
  } else {                            // weight conversion part
    int i4 = (blockIdx.x - 2048) * 256 + tid;   // float4 index 0..524287
    const float* sp; int base;
    if (i4 < 131072)      { if (i4 < 65536)  { sp = wq; base = 0; }      else { sp = wk; base = 65536; } }
    else if (i4 < 262144) { if (i4 < 196608) { sp = wv; base = 131072; } else { sp = wo; base = 196608; } }
    else if (i4 < 393216) { sp = l1; base = 262144; }
    else                  { sp = l2; base = 393216; }
    float4 v = ((const float4*)sp)[i4 - base];
    __hip_bfloat16 o[4] = {__float2bfloat16(v.x), __float2bfloat16(v.y),
                           __float2bfloat16(v.z), __float2bfloat16(v.w)};
    *(uint2*)(dst + (size_t)i4 * 4) = *(uint2*)o;
  }
}

// ---------------- LN1 + xpos(q,k) + sine pos; wave-per-row; writes acat[q;k;v]
__global__ __launch_bounds__(256) void k_ln1(
    const float* __restrict__ src_vid, const float* __restrict__ src_txt,
    const float* __restrict__ w, const float* __restrict__ b,
    __hip_bfloat16* __restrict__ acat, float* __restrict__ src2f,
    float* __restrict__ posb) {
  int row = blockIdx.x * 4 + (threadIdx.x >> 6);
  int lane = threadIdx.x & 63;
  const float* xs = (row < LVID) ? (src_vid + (size_t)row * DMOD)
                                 : (src_txt + (size_t)(row - LVID) * DMOD);
  float x[8];
  { float4 v0 = *(const float4*)&xs[lane * 8];
    float4 v1 = *(const float4*)&xs[lane * 8 + 4];
    x[0]=v0.x; x[1]=v0.y; x[2]=v0.z; x[3]=v0.w;
    x[4]=v1.x; x[5]=v1.y; x[6]=v1.z; x[7]=v1.w; }
  float s = 0.f;
#pragma unroll
  for (int i = 0; i < 8; i++) s += x[i];
#pragma unroll
  for (int st = 1; st < 64; st <<= 1) s += __shfl_xor(s, st, 64);
  float mu = s * (1.f / DMOD);
  float vs = 0.f;
#pragma unroll
  for (int i = 0; i < 8; i++) { float d = x[i] - mu; vs += d * d; }
#pragma unroll
  for (int st = 1; st < 64; st <<= 1) vs += __shfl_xor(vs, st, 64);
  float inv = rsqrtf(vs * (1.f / DMOD) + 1e-5f);
  float y[8];
  { float4 w0 = *(const float4*)&w[lane * 8];
    float4 w1 = *(const float4*)&w[lane * 8 + 4];
    float4 b0 = *(const float4*)&b[lane * 8];
    float4 b1 = *(const float4*)&b[lane * 8 + 4];
    float wv_[8] = {w0.x,w0.y,w0.z,w0.w,w1.x,w1.y,w1.z,w1.w};
    float bv_[8] = {b0.x,b0.y,b0.z,b0.w,b1.x,b1.y,b1.z,b1.w};
#pragma unroll
    for (int i = 0; i < 8; i++) y[i] = (x[i] - mu) * inv * wv_[i] + bv_[i]; }
  size_t base = (size_t)row * DMOD + lane * 8;
  if (row < LVID) {
    // v-rows of acat = bf16(LN output)
    U8 pv;
#pragma unroll
    for (int i = 0; i < 8; i++) pv.b[i] = __float2bfloat16(y[i]);
    *(uint4*)&acat[(size_t)(4096 + row) * DMOD + lane * 8] = pv.u;
    // xpos on the RAW input row
    float pq[8], pk[8];
    float l = (float)row;
#pragma unroll
    for (int p = 0; p < 4; p++) {
      int j = lane * 4 + p;
      float sj = (2.f * j + 204.8f) * (1.f / 716.8f);
      float scale = powf(sj, l * (1.f / 512.f));
      float invfreq = powf(10000.f, -(float)j * (1.f / 256.f));
      float sn, cs; sincosf(l * invfreq, &sn, &cs);
      float cq = cs * scale, sq = sn * scale;
      pq[2*p]   = x[2*p] * cq - x[2*p+1] * sq;
      pq[2*p+1] = x[2*p+1] * cq + x[2*p] * sq;
      float isc = 1.f / scale;
      float ck = cs * isc, sk = sn * isc;
      pk[2*p]   = x[2*p] * ck - x[2*p+1] * sk;
      pk[2*p+1] = x[2*p+1] * ck + x[2*p] * sk;
    }
    *(float4*)&posb[base]     = *(float4*)&pq[0];
    *(float4*)&posb[base + 4] = *(float4*)&pq[4];
    U8 pqv, pkv;
#pragma unroll
    for (int i = 0; i < 8; i++) {
      pqv.b[i] = __float2bfloat16(y[i] + pq[i]);
      pkv.b[i] = __float2bfloat16(y[i] + pk[i]);
    }
    *(uint4*)&acat[(size_t)row * DMOD + lane * 8] = pqv.u;
    *(uint4*)&acat[(size_t)(2048 + row) * DMOD + lane * 8] = pkv.u;
  } else {
    // txt rows: keep fp32 LN output + sine positional
    *(float4*)&src2f[base]     = *(float4*)&y[0];
    *(float4*)&src2f[base + 4] = *(float4*)&y[4];
    int l = row - LVID;
    float xe = (float)(l + 1) * (6.28318530717958647692f / 512.000001f);
    float ps[8];
#pragma unroll
    for (int p = 0; p < 4; p++) {
      int j = lane * 4 + p;
      float dimt = powf(10000.f, (float)j * (1.f / 256.f));
      float a = xe / dimt;
      ps[2*p] = sinf(a); ps[2*p+1] = cosf(a);
    }
    *(float4*)&posb[base]     = *(float4*)&ps[0];
    *(float4*)&posb[base + 4] = *(float4*)&ps[4];
  }
}

// ---------------- LN2: vid rows from srcA; txt rows = src_txt+src2f+posb (also
// stored to srcA); bf16 output. Wave-per-row.
__global__ __launch_bounds__(256) void k_ln2(
    const float* __restrict__ src_txt, const float* __restrict__ src2f,
    const float* __restrict__ posb, float* __restrict__ srcA,
    const float* __restrict__ w, const float* __restrict__ b,
    __hip_bfloat16* __restrict__ obf) {
  int row = blockIdx.x * 4 + (threadIdx.x >> 6);
  int lane = threadIdx.x & 63;
  size_t base = (size_t)row * DMOD + lane * 8;
  float x[8];
  if (row < LVID) {
    float4 v0 = *(const float4*)&srcA[base];
    float4 v1 = *(const float4*)&srcA[base + 4];
    x[0]=v0.x; x[1]=v0.y; x[2]=v0.z; x[3]=v0.w;
    x[4]=v1.x; x[5]=v1.y; x[6]=v1.z; x[7]=v1.w;
  } else {
    size_t tb = (size_t)(row - LVID) * DMOD + lane * 8;
#pragma unroll
    for (int i = 0; i < 8; i++) x[i] = src_txt[tb + i] + src2f[base + i] + posb[base + i];
    *(float4*)&srcA[base]     = *(float4*)&x[0];
    *(float4*)&srcA[base + 4] = *(float4*)&x[4];
  }
  float s = 0.f;
#pragma unroll
  for (int i = 0; i < 8; i++) s += x[i];
#pragma unroll
  for (int st = 1; st < 64; st <<= 1) s += __shfl_xor(s, st, 64);
  float mu = s * (1.f / DMOD);
  float vs = 0.f;
#pragma unroll
  for (int i = 0; i < 8; i++) { float d = x[i] - mu; vs += d * d; }
#pragma unroll
  for (int st = 1; st < 64; st <<= 1) vs += __shfl_xor(vs, st, 64);
  float inv = rsqrtf(vs * (1.f / DMOD) + 1e-5f);
  float4 w0 = *(const float4*)&w[lane * 8];
  float4 w1 = *(const float4*)&w[lane * 8 + 4];
  float4 b0 = *(const float4*)&b[lane * 8];
  float4 b1 = *(const float4*)&b[lane * 8 + 4];
  float wv_[8] = {w0.x,w0.y,w0.z,w0.w,w1.x,w1.y,w1.z,w1.w};
  float bv_[8] = {b0.x,b0.y,b0.z,b0.w,b1.x,b1.y,b1.z,b1.w};
  U8 o;
#pragma unroll
  for (int i = 0; i < 8; i++)
    o.b[i] = __float2bfloat16((x[i] - mu) * inv * wv_[i] + bv_[i]);
  *(uint4*)&obf[base] = o.u;
}

// ---------------- LN3: x = srcA + ffo, f32 output. Wave-per-row.
__global__ __launch_bounds__(256) void k_ln3(
    const float* __restrict__ srcA, const float* __restrict__ ffo,
    const float* __restrict__ w, const float* __restrict__ b,
    float* __restrict__ o) {
  int row = blockIdx.x * 4 + (threadIdx.x >> 6);
  int lane = threadIdx.x & 63;
  size_t base = (size_t)row * DMOD + lane * 8;
  float x[8];
  { float4 a0 = *(const float4*)&srcA[base];
    float4 a1 = *(const float4*)&srcA[base + 4];
    float4 f0 = *(const float4*)&ffo[base];
    float4 f1 = *(const float4*)&ffo[base + 4];
    x[0]=a0.x+f0.x; x[1]=a0.y+f0.y; x[2]=a0.z+f0.z; x[3]=a0.w+f0.w;
    x[4]=a1.x+f1.x; x[5]=a1.y+f1.y; x[6]=a1.z+f1.z; x[7]=a1.w+f1.w; }
  float s = 0.f;
#pragma unroll
  for (int i = 0; i < 8; i++) s += x[i];
#pragma unroll
  for (int st = 1; st < 64; st <<= 1) s += __shfl_xor(s, st, 64);
  float mu = s * (1.f / DMOD);
  float vs = 0.f;
#pragma unroll
  for (int i = 0; i < 8; i++) { float d = x[i] - mu; vs += d * d; }
#pragma unroll
  for (int st = 1; st < 64; st <<= 1) vs += __shfl_xor(vs, st, 64);
  float inv = rsqrtf(vs * (1.f / DMOD) + 1e-5f);
  float4 w0 = *(const float4*)&w[lane * 8];
  float4 w1 = *(const float4*)&w[lane * 8 + 4];
  float4 b0 = *(const float4*)&b[lane * 8];
  float4 b1 = *(const float4*)&b[lane * 8 + 4];
  float wv_[8] = {w0.x,w0.y,w0.z,w0.w,w1.x,w1.y,w1.z,w1.w};
  float bv_[8] = {b0.x,b0.y,b0.z,b0.w,b1.x,b1.y,b1.z,b1.w};
  float y[8];
#pragma unroll
  for (int i = 0; i < 8; i++) y[i] = (x[i] - mu) * inv * wv_[i] + bv_[i];
  *(float4*)&o[base]     = *(float4*)&y[0];
  *(float4*)&o[base + 4] = *(float4*)&y[4];
}

// ---------------- bf16 MFMA GEMM, 64x64 tile, BK=64 (2x32 half-tiles), LDS dbuf,
// one barrier per K-step. EPI: 0=f32, 1=bf16, 2=f32+res1+res2, 3=QKV(seg sel +
// strided out + Vtot atomics), 4=bf16+GELU.
template <int EPI>
__global__ __launch_bounds__(256) void k_gemm2(
    const __hip_bfloat16* __restrict__ A, const __hip_bfloat16* __restrict__ W0,
    const float* __restrict__ b0, const float* __restrict__ b1,
    const float* __restrict__ b2, void* __restrict__ Cv,
    const float* __restrict__ res1, const float* __restrict__ res2,
    float* __restrict__ vtot, int M, int N, int K) {
  __shared__ __hip_bfloat16 sA[2][4096];
  __shared__ __hip_bfloat16 sB[2][4096];
  int tid = threadIdx.x, lane = tid & 63, w = tid >> 6;
  int c16 = lane & 15, q4 = lane >> 4;
  int bm = blockIdx.y * 64, bn = blockIdx.x * 64;
  int seg = (EPI == 3) ? (bm >> 11) : 0;
  const __hip_bfloat16* Wp = (EPI == 3) ? (W0 + (size_t)seg * N * K) : W0;
  int srow = tid >> 2, scol = (tid & 3) * 8;
  const __hip_bfloat16* gA = A + (size_t)(bm + srow) * K + scol;
  const __hip_bfloat16* gB = Wp + (size_t)(bn + srow) * K + scol;
  auto stage = [&](int buf, int k0) {
    gload_lds16(gA + k0,      &sA[buf][0]    + (size_t)tid * 8);
    gload_lds16(gA + k0 + 32, &sA[buf][2048] + (size_t)tid * 8);
    gload_lds16(gB + k0,      &sB[buf][0]    + (size_t)tid * 8);
    gload_lds16(gB + k0 + 32, &sB[buf][2048] + (size_t)tid * 8);
  };
  f32x4 acc[2][2];
  { f32x4 z = {0.f,0.f,0.f,0.f}; acc[0][0]=z; acc[0][1]=z; acc[1][0]=z; acc[1][1]=z; }
  int wm = w & 1, wn = w >> 1;
  const int S = K >> 6;
  stage(0, 0);
  for (int s = 0; s < S; s++) {
    __syncthreads();
    if (s + 1 < S) stage((s + 1) & 1, (s + 1) * 64);
    int bf = s & 1;
#pragma unroll
    for (int kc = 0; kc < 2; kc++) {
      bf16x8 a0  = *(const bf16x8*)&sA[bf][kc*2048 + (wm*32 + c16)*32 + q4*8];
      bf16x8 a1  = *(const bf16x8*)&sA[bf][kc*2048 + (wm*32 + 16 + c16)*32 + q4*8];
      bf16x8 bv0 = *(const bf16x8*)&sB[bf][kc*2048 + (wn*32 + c16)*32 + q4*8];
      bf16x8 bv1 = *(const bf16x8*)&sB[bf][kc*2048 + (wn*32 + 16 + c16)*32 + q4*8];
      acc[0][0] = mfma_bf16(a0, bv0, acc[0][0]);
      acc[0][1] = mfma_bf16(a0, bv1, acc[0][1]);
      acc[1][0] = mfma_bf16(a1, bv0, acc[1][0]);
      acc[1][1] = mfma_bf16(a1, bv1, acc[1][1]);
    }
  }
  float alpha = (EPI == 3 && seg == 0) ? 0.125f : 1.f;
  const float* bp = (EPI == 3) ? (seg == 0 ? b0 : (seg == 1 ? b1 : b2)) : b0;
  float vsum[2] = {0.f, 0.f};
#pragma unroll
  for (int t = 0; t < 2; t++) {
#pragma unroll
    for (int u = 0; u < 2; u++) {
      int n = bn + wn*32 + u*16 + c16;
      float bs = bp[n];
#pragma unroll
      for (int r = 0; r < 4; r++) {
        int m = bm + wm*32 + t*16 + q4*4 + r;
        float v = (acc[t][u][r] + bs) * alpha;
        if (EPI == 4) v = 0.5f * v * (1.f + erff(v * 0.70710678118654752f));
        if (EPI == 0) {
          ((float*)Cv)[(size_t)m * N + n] = v;
        } else if (EPI == 1 || EPI == 4) {
          ((__hip_bfloat16*)Cv)[(size_t)m * N + n] = __float2bfloat16(v);
        } else if (EPI == 2) {
          size_t off = (size_t)m * N + n;
          ((float*)Cv)[off] = v + res1[off] + res2[off];
        } else {  // EPI == 3
          __hip_bfloat16 vb = __float2bfloat16(v);
          ((__hip_bfloat16*)Cv)[(size_t)(m & 2047) * 1536 + seg * 512 + n] = vb;
          if (seg == 2) vsum[u] += __bfloat162float(vb);
        }
      }
    }
  }
  if (EPI == 3 && seg == 2) {
#pragma unroll
    for (int u = 0; u < 2; u++) {
      float s2 = vsum[u];
      s2 += __shfl_xor(s2, 16, 64);
      s2 += __shfl_xor(s2, 32, 64);
      if (q4 == 0) atomicAdd(&vtot[bn + wn*32 + u*16 + c16], s2);
    }
  }
}

// ---------------- retention attention v2: S^T layout, one barrier/tile
__global__ __launch_bounds__(256) void k_attn(
    const __hip_bfloat16* __restrict__ qkv,   // [2048][1536] = q|k|v
    const float* __restrict__ premask2,       // [2048][2048], includes log2e
    const float* __restrict__ Vtot,           // [512]
    __hip_bfloat16* __restrict__ outp) {      // [2048][512]
  __shared__ __hip_bfloat16 sQ[64][72];
  __shared__ __hip_bfloat16 sK[2][64][72];
  __shared__ __hip_bfloat16 sVt[2][64][72];   // [d][j]
  __shared__ __hip_bfloat16 sP[64][72];       // [q][j]
  __shared__ float sVa[4][64];
  int i0 = blockIdx.x * 64, h = blockIdx.y;
  int tid = threadIdx.x, lane = tid & 63, w = tid >> 6;
  int c16 = lane & 15, q4 = lane >> 4;
  {  // stage Q
    int r = tid >> 2, c0 = (tid & 3) * 16;
    const __hip_bfloat16* g = qkv + (size_t)(i0 + r) * 1536 + h * 64 + c0;
    *(uint4*)&sQ[r][c0]     = *(const uint4*)g;
    *(uint4*)&sQ[r][c0 + 8] = *(const uint4*)(g + 8);
  }
  int thi = i0 >> 6;
  int tlo = (i0 > 900) ? ((i0 - 900) >> 6) : 0;
  float rm = 0.f, rz = 0.f;       // per-lane: q-row = i0 + w*16 + c16
  f32x4 O[4];
  { f32x4 z = {0.f,0.f,0.f,0.f}; O[0]=z; O[1]=z; O[2]=z; O[3]=z; }
  float vacc = 0.f;
  int kr = tid >> 2, kc = (tid & 3) * 16;
  uint4 pk0, pk1;
  U8 pv0, pv1;
  {  // prefetch tile tlo
    const __hip_bfloat16* gk = qkv + (size_t)(tlo*64 + kr) * 1536 + 512 + h*64 + kc;
    pk0 = *(const uint4*)gk; pk1 = *(const uint4*)(gk + 8);
    const __hip_bfloat16* gv = qkv + (size_t)(tlo*64 + w*16) * 1536 + 1024 + h*64 + lane;
#pragma unroll
    for (int j = 0; j < 8; j++) pv0.b[j] = gv[(size_t)j * 1536];
#pragma unroll
    for (int j = 0; j < 8; j++) pv1.b[j] = gv[(size_t)(j + 8) * 1536];
  }
  for (int t = tlo; t <= thi; t++) {
    int buf = (t - tlo) & 1;
    *(uint4*)&sK[buf][kr][kc]       = pk0;
    *(uint4*)&sK[buf][kr][kc + 8]   = pk1;
    *(uint4*)&sVt[buf][lane][w*16]     = pv0.u;
    *(uint4*)&sVt[buf][lane][w*16 + 8] = pv1.u;
#pragma unroll
    for (int j = 0; j < 8; j++) vacc += __bfloat162float(pv0.b[j]);
#pragma unroll
    for (int j = 0; j < 8; j++) vacc += __bfloat162float(pv1.b[j]);
    __syncthreads();
    if (t < thi) {   // prefetch next tile, overlaps compute
      const __hip_bfloat16* gk = qkv + (size_t)((t+1)*64 + kr) * 1536 + 512 + h*64 + kc;
      pk0 = *(const uint4*)gk; pk1 = *(const uint4*)(gk + 8);
      const __hip_bfloat16* gv = qkv + (size_t)((t+1)*64 + w*16) * 1536 + 1024 + h*64 + lane;
#pragma unroll
      for (int j = 0; j < 8; j++) pv0.b[j] = gv[(size_t)j * 1536];
#pragma unroll
      for (int j = 0; j < 8; j++) pv1.b[j] = gv[(size_t)(j + 8) * 1536];
    }
    // ---- S^T = K·Q^T : D[j][q]; wave w owns q-cols w*16..+15
    bf16x8 bq0 = *(const bf16x8*)&sQ[w*16 + c16][q4*8];
    bf16x8 bq1 = *(const bf16x8*)&sQ[w*16 + c16][32 + q4*8];
    f32x4 St[4];
#pragma unroll
    for (int jt = 0; jt < 4; jt++) {
      f32x4 z = {0.f,0.f,0.f,0.f};
      bf16x8 a0 = *(const bf16x8*)&sK[buf][jt*16 + c16][q4*8];
      bf16x8 a1 = *(const bf16x8*)&sK[buf][jt*16 + c16][32 + q4*8];
      z = mfma_bf16(a0, bq0, z);
      z = mfma_bf16(a1, bq1, z);
      St[jt] = z;   // lane: q = w*16+c16, j = jt*16 + q4*4 + r
    }
    // ---- mask (premask2 includes log2e); float4 per jt
    int qg = i0 + w*16 + c16;
    float lg[4][4];
    float tmax = -3.0e38f;
#pragma unroll
    for (int jt = 0; jt < 4; jt++) {
      float4 pm = *(const float4*)&premask2[(size_t)qg * 2048 + t*64 + jt*16 + q4*4];
      lg[jt][0] = St[jt][0] * pm.x; lg[jt][1] = St[jt][1] * pm.y;
      lg[jt][2] = St[jt][2] * pm.z; lg[jt][3] = St[jt][3] * pm.w;
#pragma unroll
      for (int r = 0; r < 4; r++) tmax = fmaxf(tmax, lg[jt][r]);
    }
    tmax = fmaxf(tmax, __shfl_xor(tmax, 16, 64));
    tmax = fmaxf(tmax, __shfl_xor(tmax, 32, 64));
    float mn = fmaxf(rm, tmax);
    float al = exp2f(rm - mn);
    rm = mn;
    float zp = 0.f;
#pragma unroll
    for (int jt = 0; jt < 4; jt++) {
      U8 e4; // pack 4 bf16 (use low half)
      float e0 = exp2f(lg[jt][0] - rm), e1 = exp2f(lg[jt][1] - rm);
      float e2 = exp2f(lg[jt][2] - rm), e3 = exp2f(lg[jt][3] - rm);
      zp += e0 + e1 + e2 + e3;
      e4.b[0] = __float2bfloat16(e0); e4.b[1] = __float2bfloat16(e1);
      e4.b[2] = __float2bfloat16(e2); e4.b[3] = __float2bfloat16(e3);
      *(uint2*)&sP[w*16 + c16][jt*16 + q4*4] = *(uint2*)&e4.b[0];
    }
    zp += __shfl_xor(zp, 16, 64);
    zp += __shfl_xor(zp, 32, 64);
    rz = rz * al + zp;
    // ---- rescale O (alpha redistributed to row-layout lanes)
    float alr[4];
#pragma unroll
    for (int r = 0; r < 4; r++) alr[r] = __shfl(al, q4*4 + r, 64);
#pragma unroll
    for (int dt = 0; dt < 4; dt++)
#pragma unroll
      for (int r = 0; r < 4; r++) O[dt][r] *= alr[r];
    // ---- O += P·V (P rows intra-wave; B from sVt)
    bf16x8 ap0 = *(const bf16x8*)&sP[w*16 + c16][q4*8];
    bf16x8 ap1 = *(const bf16x8*)&sP[w*16 + c16][32 + q4*8];
#pragma unroll
    for (int dt = 0; dt < 4; dt++) {
      bf16x8 bv0 = *(const bf16x8*)&sVt[buf][dt*16 + c16][q4*8];
      bf16x8 bv1 = *(const bf16x8*)&sVt[buf][dt*16 + c16][32 + q4*8];
      O[dt] = mfma_bf16(ap0, bv0, O[dt]);
      O[dt] = mfma_bf16(ap1, bv1, O[dt]);
    }
  }
  sVa[w][lane] = vacc;
  __syncthreads();
  float rmr[4], rzr[4];
#pragma unroll
  for (int r = 0; r < 4; r++) {
    rmr[r] = __shfl(rm, q4*4 + r, 64);
    rzr[r] = __shfl(rz, q4*4 + r, 64);
  }
  float nu = (float)(2048 - 64 * (thi - tlo + 1));
#pragma unroll
  for (int dt = 0; dt < 4; dt++) {
    int d = dt*16 + c16;
    float va = sVa[0][d] + sVa[1][d] + sVa[2][d] + sVa[3][d];
    float vu = Vtot[h*64 + d] - va;
#pragma unroll
    for (int r = 0; r < 4; r++) {
      float eu = exp2f(-rmr[r]);
      float o = (O[dt][r] + eu * vu) / (rzr[r] + nu * eu);
      outp[(size_t)(i0 + w*16 + q4*4 + r) * DMOD + h*64 + d] = __float2bfloat16(o);
    }
  }
}

// ----------------------------------------------------------------- launcher
extern "C" void kernel_launch(void* const* d_in, const int* in_sizes, int n_in,
                              void* d_out, int out_size, void* d_ws, size_t ws_size,
                              hipStream_t stream) {
  const float* src_vid = (const float*)d_in[0];
  const float* src_txt = (const float*)d_in[1];
  const float* ln1_w = (const float*)d_in[2];
  const float* ln1_b = (const float*)d_in[3];
  const float* wq = (const float*)d_in[4];
  const float* bq = (const float*)d_in[5];
  const float* wk = (const float*)d_in[6];
  const float* bk = (const float*)d_in[7];
  const float* wv = (const float*)d_in[8];
  const float* bv = (const float*)d_in[9];
  const float* wo = (const float*)d_in[10];
  const float* bo = (const float*)d_in[11];
  const float* lin1_w = (const float*)d_in[12];
  const float* lin1_b = (const float*)d_in[13];
  const float* lin2_w = (const float*)d_in[14];
  const float* lin2_b = (const float*)d_in[15];
  const float* ln2_w = (const float*)d_in[16];
  const float* ln2_b = (const float*)d_in[17];
  const float* ln3_w = (const float*)d_in[18];
  const float* ln3_b = (const float*)d_in[19];
  const float* lw = (const float*)d_in[20];
  float* out = (float*)d_out;

  // ws is 256 MiB (harness fill evidence) — no aliasing needed.
  char* wsb = (char*)d_ws;
  float* premask2       = (float*)(wsb + 0);                       // 16 MiB
  __hip_bfloat16* wqb   = (__hip_bfloat16*)(wsb + 16777216);       // 4 MiB: wq|wk|wv|wo|l1|l2
  __hip_bfloat16* wob   = wqb + 786432;
  __hip_bfloat16* l1b   = wqb + 1048576;
  __hip_bfloat16* l2b   = wqb + 1572864;
  __hip_bfloat16* acat  = (__hip_bfloat16*)(wsb + 20971520);       // 6 MiB [6144][512]
  __hip_bfloat16* qkvb  = (__hip_bfloat16*)(wsb + 27262976);       // 6 MiB [2048][1536]
  __hip_bfloat16* vattb = (__hip_bfloat16*)(wsb + 33554432);       // 2 MiB
  float* srcA           = (float*)(wsb + 35651584);                // 5 MiB
  float* src2f          = (float*)(wsb + 40894464);                // 5 MiB
  float* posb           = (float*)(wsb + 46137344);                // 5 MiB
  __hip_bfloat16* s2b   = (__hip_bfloat16*)(wsb + 51380224);       // 2.5 MiB
  __hip_bfloat16* hidb  = (__hip_bfloat16*)(wsb + 54525952);       // 5 MiB
  float* ffo            = (float*)(wsb + 59768832);                // 5 MiB
  float* Vtot           = (float*)(wsb + 65011712);                // 2 KiB

  hipMemsetAsync(out + 1310720, 0, sizeof(float), stream);   // loss slot
  hipMemsetAsync(Vtot, 0, 512 * sizeof(float), stream);

  k_prep<<<4096, 256, 0, stream>>>(lw, premask2, out + 1310720,
                                   wq, wk, wv, wo, lin1_w, lin2_w, wqb);
  k_ln1<<<640, 256, 0, stream>>>(src_vid, src_txt, ln1_w, ln1_b,
                                 acat, src2f, posb);
  // QKV fused: M=6144 (q|k|v rows), N=512, K=512; strided out + Vtot atomics
  k_gemm2<3><<<dim3(8, 96), 256, 0, stream>>>(acat, wqb, bq, bk, bv,
      qkvb, nullptr, nullptr, Vtot, 6144, 512, 512);
  k_attn<<<dim3(32, 8), 256, 0, stream>>>(qkvb, premask2, Vtot, vattb);
  // O-proj with fused residual: srcA(vid) = vatt@wo^T + bo + src_vid + posb
  k_gemm2<2><<<dim3(8, 32), 256, 0, stream>>>(vattb, wob, bo, nullptr, nullptr,
      srcA, src_vid, posb, nullptr, 2048, 512, 512);
  k_ln2<<<640, 256, 0, stream>>>(src_txt, src2f, posb, srcA, ln2_w, ln2_b, s2b);
  k_gemm2<4><<<dim3(16, 40), 256, 0, stream>>>(s2b, l1b, lin1_b, nullptr, nullptr,
      hidb, nullptr, nullptr, nullptr, 2560, 1024, 512);
  k_gemm2<0><<<dim3(8, 40), 256, 0, stream>>>(hidb, l2b, lin2_b, nullptr, nullptr,
      ffo, nullptr, nullptr, nullptr, 2560, 512, 1024);
  k_ln3<<<640, 256, 0, stream>>>(srcA, ffo, ln3_w, ln3_b, out);
}